// Round 4
// baseline (510.292 us; speedup 1.0000x reference)
//
#include <hip/hip_runtime.h>
#include <math.h>

#define NB  8
#define SEQ 2048
#define DIM 512

typedef short v8s __attribute__((ext_vector_type(8)));
typedef float v4f __attribute__((ext_vector_type(4)));

__device__ __forceinline__ unsigned short f2bf(float f) {
    unsigned int u = __float_as_uint(f);
    u += 0x7fffu + ((u >> 16) & 1u);
    return (unsigned short)(u >> 16);
}
__device__ __forceinline__ float bf2f(unsigned short h) {
    return __uint_as_float((unsigned int)h << 16);
}
// async 16B global->LDS. LDS dest = lptr(wave-uniform) + lane*16.
__device__ __forceinline__ void async16(const unsigned short* g, unsigned short* l) {
    __builtin_amdgcn_global_load_lds(
        (const __attribute__((address_space(1))) unsigned int*)g,
        (__attribute__((address_space(3))) unsigned int*)l, 16, 0, 0);
}

// fp32 -> bf16 elementwise
__global__ __launch_bounds__(256)
void conv_bf16(const float* __restrict__ x, unsigned short* __restrict__ y)
{
    int i = blockIdx.x * 256 + threadIdx.x;
    float4 v = ((const float4*)x)[i];
    ushort4 o; o.x = f2bf(v.x); o.y = f2bf(v.y); o.z = f2bf(v.z); o.w = f2bf(v.w);
    ((ushort4*)y)[i] = o;
}

// ---------------------------------------------------------------------------
// Single-bf16 MFMA projection: Y[m][e] = sum_d X[m][d]*W[e][d] + bias[e]
// ---------------------------------------------------------------------------
template<int MODE>
__global__ __launch_bounds__(256, 2)
void proj_sgl(const unsigned short* __restrict__ Xbf, const float* __restrict__ W,
              const float* __restrict__ bias, unsigned short* __restrict__ Y)
{
    __shared__ __align__(16) unsigned short As[128 * 64];
    __shared__ __align__(16) unsigned short Bs[128 * 64];

    const int t = threadIdx.x, wave = t >> 6, lane = t & 63;
    const int l15 = lane & 15, quad = lane >> 4;
    const int m0 = blockIdx.x * 128, e0 = blockIdx.y * 128;

    v4f hacc[2][8];
#pragma unroll
    for (int mt = 0; mt < 2; mt++)
#pragma unroll
        for (int nt = 0; nt < 8; nt++) hacc[mt][nt] = (v4f){0.f, 0.f, 0.f, 0.f};

    const int lr8 = lane >> 3, lc8 = lane & 7;

#define STAGE_A(bk)                                                            \
    _Pragma("unroll") for (int i = 0; i < 4; i++) {                            \
        int row = wave * 32 + i * 8 + lr8;                                     \
        int lc = lc8 ^ (row & 7);                                              \
        async16(Xbf + (size_t)(m0 + row) * DIM + (bk) * 64 + lc * 8,           \
                &As[(wave * 32 + i * 8) * 64]);                                \
    }
#define STAGE_B(bk)                                                            \
    _Pragma("unroll") for (int j = 0; j < 8; j++) {                            \
        int u = t * 8 + j;                                                     \
        int row = u >> 4, c4 = u & 15;                                         \
        float4 wv = *(const float4*)(W + (size_t)(e0 + row) * DIM + (bk) * 64 + c4 * 4); \
        ushort4 o = make_ushort4(f2bf(wv.x), f2bf(wv.y), f2bf(wv.z), f2bf(wv.w)); \
        int sc = (c4 >> 1) ^ (row & 7);                                        \
        *(ushort4*)&Bs[row * 64 + sc * 8 + (c4 & 1) * 4] = o;                  \
    }

    STAGE_A(0) STAGE_B(0)
    for (int bk = 0; bk < 8; bk++) {
        __syncthreads();
#pragma unroll
        for (int kc = 0; kc < 2; kc++) {
            v8s a[2];
#pragma unroll
            for (int mt = 0; mt < 2; mt++) {
                int row = wave * 32 + mt * 16 + l15;
                a[mt] = *(const v8s*)&As[row * 64 + (((kc * 4 + quad) ^ (row & 7)) * 8)];
            }
#pragma unroll
            for (int nt = 0; nt < 8; nt++) {
                int er = nt * 16 + l15;
                v8s bfr = *(const v8s*)&Bs[er * 64 + (((kc * 4 + quad) ^ (er & 7)) * 8)];
#pragma unroll
                for (int mt = 0; mt < 2; mt++)
                    hacc[mt][nt] = __builtin_amdgcn_mfma_f32_16x16x32_bf16(a[mt], bfr, hacc[mt][nt], 0, 0, 0);
            }
        }
        __syncthreads();
        if (bk + 1 < 8) { STAGE_A(bk + 1) STAGE_B(bk + 1) }
    }
#undef STAGE_A
#undef STAGE_B

#pragma unroll
    for (int mt = 0; mt < 2; mt++)
#pragma unroll
        for (int nt = 0; nt < 8; nt++) {
            int col = e0 + nt * 16 + l15;
            float bb = bias[col];
            if (MODE == 0) {
#pragma unroll
                for (int r = 0; r < 4; r++) {
                    int row = m0 + wave * 32 + mt * 16 + quad * 4 + r;
                    Y[(size_t)row * DIM + col] = f2bf(hacc[mt][nt][r] + bb);
                }
            } else {
                int rowb = m0 + wave * 32 + mt * 16 + quad * 4;
                int bidx = rowb >> 11, n = rowb & 2047;
                ushort4 o = make_ushort4(f2bf(hacc[mt][nt][0] + bb), f2bf(hacc[mt][nt][1] + bb),
                                         f2bf(hacc[mt][nt][2] + bb), f2bf(hacc[mt][nt][3] + bb));
                *(ushort4*)&Y[(size_t)bidx * DIM * SEQ + (size_t)col * SEQ + n] = o;
            }
        }
}

// ---------------------------------------------------------------------------
// Split (hi/lo) MFMA projection for the output layer: fp32-accurate.
// ---------------------------------------------------------------------------
__global__ __launch_bounds__(256, 2)
void proj_split(const unsigned short* __restrict__ Ahi, const unsigned short* __restrict__ Alo,
                const float* __restrict__ W, const float* __restrict__ bias,
                float* __restrict__ Y)
{
    __shared__ __align__(16) unsigned short Ah[128 * 64];
    __shared__ __align__(16) unsigned short Al[128 * 64];
    __shared__ __align__(16) unsigned short Bh[128 * 64];
    __shared__ __align__(16) unsigned short Bl[128 * 64];

    const int t = threadIdx.x, wave = t >> 6, lane = t & 63;
    const int l15 = lane & 15, quad = lane >> 4;
    const int m0 = blockIdx.x * 128, e0 = blockIdx.y * 128;

    v4f hacc[2][8];
#pragma unroll
    for (int mt = 0; mt < 2; mt++)
#pragma unroll
        for (int nt = 0; nt < 8; nt++) hacc[mt][nt] = (v4f){0.f, 0.f, 0.f, 0.f};

    const int lr8 = lane >> 3, lc8 = lane & 7;

#define STAGE_A2(bk)                                                           \
    _Pragma("unroll") for (int i = 0; i < 4; i++) {                            \
        int row = wave * 32 + i * 8 + lr8;                                     \
        int lc = lc8 ^ (row & 7);                                              \
        size_t ga = (size_t)(m0 + row) * DIM + (bk) * 64 + lc * 8;             \
        async16(Ahi + ga, &Ah[(wave * 32 + i * 8) * 64]);                      \
        async16(Alo + ga, &Al[(wave * 32 + i * 8) * 64]);                      \
    }
#define STAGE_B2(bk)                                                           \
    _Pragma("unroll") for (int j = 0; j < 8; j++) {                            \
        int u = t * 8 + j;                                                     \
        int row = u >> 4, c4 = u & 15;                                         \
        float4 wv = *(const float4*)(W + (size_t)(e0 + row) * DIM + (bk) * 64 + c4 * 4); \
        ushort4 oh = make_ushort4(f2bf(wv.x), f2bf(wv.y), f2bf(wv.z), f2bf(wv.w)); \
        ushort4 ol = make_ushort4(f2bf(wv.x - bf2f(oh.x)), f2bf(wv.y - bf2f(oh.y)), \
                                  f2bf(wv.z - bf2f(oh.z)), f2bf(wv.w - bf2f(oh.w))); \
        int sc = (c4 >> 1) ^ (row & 7);                                        \
        int sa = row * 64 + sc * 8 + (c4 & 1) * 4;                             \
        *(ushort4*)&Bh[sa] = oh;                                               \
        *(ushort4*)&Bl[sa] = ol;                                               \
    }

    STAGE_A2(0) STAGE_B2(0)
    for (int bk = 0; bk < 8; bk++) {
        __syncthreads();
#pragma unroll
        for (int kc = 0; kc < 2; kc++) {
            v8s ah[2], al[2];
#pragma unroll
            for (int mt = 0; mt < 2; mt++) {
                int row = wave * 32 + mt * 16 + l15;
                int sa = row * 64 + (((kc * 4 + quad) ^ (row & 7)) * 8);
                ah[mt] = *(const v8s*)&Ah[sa];
                al[mt] = *(const v8s*)&Al[sa];
            }
#pragma unroll
            for (int nt = 0; nt < 8; nt++) {
                int er = nt * 16 + l15;
                int sb = er * 64 + (((kc * 4 + quad) ^ (er & 7)) * 8);
                v8s bh = *(const v8s*)&Bh[sb];
                v8s bl = *(const v8s*)&Bl[sb];
#pragma unroll
                for (int mt = 0; mt < 2; mt++) {
                    hacc[mt][nt] = __builtin_amdgcn_mfma_f32_16x16x32_bf16(ah[mt], bh, hacc[mt][nt], 0, 0, 0);
                    hacc[mt][nt] = __builtin_amdgcn_mfma_f32_16x16x32_bf16(al[mt], bh, hacc[mt][nt], 0, 0, 0);
                    hacc[mt][nt] = __builtin_amdgcn_mfma_f32_16x16x32_bf16(ah[mt], bl, hacc[mt][nt], 0, 0, 0);
                }
            }
        }
        __syncthreads();
        if (bk + 1 < 8) { STAGE_A2(bk + 1) STAGE_B2(bk + 1) }
    }
#undef STAGE_A2
#undef STAGE_B2

#pragma unroll
    for (int mt = 0; mt < 2; mt++)
#pragma unroll
        for (int nt = 0; nt < 8; nt++) {
            int col = e0 + nt * 16 + l15;
            float bb = bias[col];
#pragma unroll
            for (int r = 0; r < 4; r++) {
                int row = m0 + wave * 32 + mt * 16 + quad * 4 + r;
                Y[(size_t)row * DIM + col] = hacc[mt][nt][r] + bb;
            }
        }
}

// ---------------------------------------------------------------------------
// Flash attention v6: 32 q-rows/block, 64-key tiles, 8 waves.
// Grid (NB, SEQ/32) = 512 blocks -> 2 truly-resident blocks/CU (the r3
// lesson: resources allowed 2 blocks but the 256-block grid supplied 1).
// QK: wave = (strip = w&1: 16 q-rows) x (kq = w>>1: 16-key quarter), full D
// in regs (qf[16]).  Softmax in QK layout: shfl_xor over l15 + Mp/Sp[4][32]
// quarter-combine.  PV: wave owns 64 d-cols; Ps[32][64] chunk-XOR swizzled.
// LDS = 64K(Ks)+4K(Ps)+1.2K = 70.8 KB -> 2 blocks/CU at <=124 VGPR.
// blockIdx.x = batch -> XCD-pinned K/V (proven: FETCH 24.7 MB in r3).
// ---------------------------------------------------------------------------
__global__ __launch_bounds__(512, 2)
void flash_mfma5(const unsigned short* __restrict__ qbf,
                 const unsigned short* __restrict__ ctxbf,
                 const unsigned short* __restrict__ vT,
                 unsigned short* __restrict__ hhi,
                 unsigned short* __restrict__ hlo)
{
    __shared__ __align__(16) unsigned short Ks[64 * 512];  // 64 KB swizzled [key][d]
    __shared__ __align__(16) unsigned short Ps[32 * 64];   // 4 KB [row][key] bf16, chunk^(row&7)
    __shared__ float Mp[4][32];                            // per-quarter row max partials
    __shared__ float Sp[4][32];                            // per-quarter row sum partials
    __shared__ float alphaS[32];

    const int t = threadIdx.x;
    const int wave = t >> 6, lane = t & 63;
    const int l15 = lane & 15, quad = lane >> 4;
    const int strip = wave & 1, kq = wave >> 1;
    const int qrow0 = strip * 16 + quad * 4;     // this lane's 4 softmax rows
    const int b = blockIdx.x, m0 = blockIdx.y * 32;

    const unsigned short* ctxb = ctxbf + (size_t)b * SEQ * DIM;
    const unsigned short* vTb  = vT    + (size_t)b * DIM * SEQ;
    const float scale = 0.044194173824159216f;   // 1/sqrt(512)

    // Q fragments: rows m0 + strip*16 + l15 (replicated across key-quarters)
    v8s qf[16];
    {
        const unsigned short* qrow = qbf + ((size_t)b * SEQ + m0 + strip * 16 + l15) * DIM;
#pragma unroll
        for (int kc = 0; kc < 16; kc++)
            qf[kc] = *(const v8s*)(qrow + kc * 32 + quad * 8);
    }
    v4f hacc[2][4];   // [Mtile][dt], cols wave*64 + dt*16
#pragma unroll
    for (int m = 0; m < 2; m++)
#pragma unroll
        for (int dt = 0; dt < 4; dt++) hacc[m][dt] = (v4f){0.f, 0.f, 0.f, 0.f};

    float M[4], L[4];
#pragma unroll
    for (int r = 0; r < 4; r++) { M[r] = -INFINITY; L[r] = 0.f; }

    // stage K[0]: 8 rows/wave
#pragma unroll
    for (int i = 0; i < 8; i++) {
        int row = wave * 8 + i;
        async16(ctxb + (size_t)row * DIM + (size_t)(lane ^ (row & 7)) * 8, &Ks[row * 512]);
    }

    for (int kt = 0; kt < SEQ / 64; kt++) {
        __syncthreads();   // B0: K[kt] staged & visible
        // ---- S = Q.K^T: 16 rows x 16 keys per wave (full D) ----
        v4f sacc = (v4f){0.f, 0.f, 0.f, 0.f};
        __builtin_amdgcn_s_setprio(1);
#pragma unroll
        for (int kc = 0; kc < 16; kc++) {
            int key = kq * 16 + l15;
            v8s kf = *(const v8s*)&Ks[key * 512 + (((kc * 4 + quad) ^ (key & 7)) * 8)];
            sacc = __builtin_amdgcn_mfma_f32_16x16x32_bf16(qf[kc], kf, sacc, 0, 0, 0);
        }
        __builtin_amdgcn_s_setprio(0);
        // ---- in-layout row max: reduce over l15 (16 lanes) ----
        float s[4], mx[4];
#pragma unroll
        for (int r = 0; r < 4; r++) {
            s[r] = sacc[r] * scale;
            mx[r] = s[r];
        }
#pragma unroll
        for (int off = 1; off < 16; off <<= 1)
#pragma unroll
            for (int r = 0; r < 4; r++)
                mx[r] = fmaxf(mx[r], __shfl_xor(mx[r], off, 64));
        if (l15 == 0) {
#pragma unroll
            for (int r = 0; r < 4; r++) Mp[kq][qrow0 + r] = mx[r];
        }
        __syncthreads();   // B1: Mp complete, Ks reads done
        // ---- combine quarters, exponentiate in-layout, write swizzled Ps ----
        float Mn[4], al[4], sm[4];
#pragma unroll
        for (int r = 0; r < 4; r++) {
            int row = qrow0 + r;
            float mo = fmaxf(fmaxf(Mp[0][row], Mp[1][row]), fmaxf(Mp[2][row], Mp[3][row]));
            Mn[r] = fmaxf(M[r], mo);
            al[r] = __expf(M[r] - Mn[r]);
            float p = __expf(s[r] - Mn[r]);
            sm[r] = p;
            int k = kq * 16 + l15;
            Ps[row * 64 + (((k >> 3) ^ (row & 7)) << 3) + (k & 7)] = f2bf(p);
        }
#pragma unroll
        for (int off = 1; off < 16; off <<= 1)
#pragma unroll
            for (int r = 0; r < 4; r++)
                sm[r] += __shfl_xor(sm[r], off, 64);
        if (l15 == 0) {
#pragma unroll
            for (int r = 0; r < 4; r++) Sp[kq][qrow0 + r] = sm[r];
            if (kq == 0) {
#pragma unroll
                for (int r = 0; r < 4; r++) alphaS[qrow0 + r] = al[r];
            }
        }
        __syncthreads();   // B2: Ps/Sp/alpha ready
        // ---- update running stats (identical across the strip's kq waves) ----
#pragma unroll
        for (int r = 0; r < 4; r++) {
            int row = qrow0 + r;
            L[r] = L[r] * al[r] + (Sp[0][row] + Sp[1][row]) + (Sp[2][row] + Sp[3][row]);
            M[r] = Mn[r];
        }
        // ---- issue K[kt+1] (in flight across PV; drained at next B0) ----
        if (kt + 1 < SEQ / 64) {
#pragma unroll
            for (int i = 0; i < 8; i++) {
                int row = wave * 8 + i;
                async16(ctxb + (size_t)((kt + 1) * 64 + row) * DIM + (size_t)(lane ^ (row & 7)) * 8,
                        &Ks[row * 512]);
            }
        }
        // ---- V fragments (L2-hot; latency covered by sibling block) ----
        v8s vf[4][2];
#pragma unroll
        for (int dt = 0; dt < 4; dt++)
#pragma unroll
            for (int kc2 = 0; kc2 < 2; kc2++)
                vf[dt][kc2] = *(const v8s*)(vTb + (size_t)(wave * 64 + dt * 16 + l15) * SEQ
                                            + kt * 64 + kc2 * 32 + quad * 8);
        // ---- PV: rescale + h += P.V ----
#pragma unroll
        for (int m = 0; m < 2; m++) {
            v4f a4;
#pragma unroll
            for (int r = 0; r < 4; r++) a4[r] = alphaS[m * 16 + quad * 4 + r];
#pragma unroll
            for (int dt = 0; dt < 4; dt++) hacc[m][dt] *= a4;
        }
        __builtin_amdgcn_s_setprio(1);
#pragma unroll
        for (int kc2 = 0; kc2 < 2; kc2++)
#pragma unroll
            for (int m = 0; m < 2; m++) {
                int row = m * 16 + l15;
                v8s pa = *(const v8s*)&Ps[row * 64 + (((kc2 * 4 + quad) ^ (row & 7)) << 3)];
#pragma unroll
                for (int dt = 0; dt < 4; dt++)
                    hacc[m][dt] = __builtin_amdgcn_mfma_f32_16x16x32_bf16(pa, vf[dt][kc2], hacc[m][dt], 0, 0, 0);
            }
        __builtin_amdgcn_s_setprio(0);
    }

    // ---- epilogue: h/L, split hi/lo ----
    __syncthreads();
    if (kq == 0 && l15 == 0) {
#pragma unroll
        for (int r = 0; r < 4; r++) alphaS[qrow0 + r] = 1.0f / L[r];
    }
    __syncthreads();
#pragma unroll
    for (int m = 0; m < 2; m++) {
#pragma unroll
        for (int r = 0; r < 4; r++) {
            float invL = alphaS[m * 16 + quad * 4 + r];
            int grow = m0 + m * 16 + quad * 4 + r;
#pragma unroll
            for (int dt = 0; dt < 4; dt++) {
                float o = hacc[m][dt][r] * invL;
                unsigned short hi = f2bf(o);
                float lof = o - bf2f(hi);
                size_t idx = ((size_t)b * SEQ + grow) * DIM + wave * 64 + dt * 16 + l15;
                hhi[idx] = hi;
                hlo[idx] = f2bf(lof);
            }
        }
    }
}

// ---------------------------------------------------------------------------
extern "C" void kernel_launch(void* const* d_in, const int* in_sizes, int n_in,
                              void* d_out, int out_size, void* d_ws, size_t ws_size,
                              hipStream_t stream)
{
    const float* query   = (const float*)d_in[0];
    const float* context = (const float*)d_in[1];
    const float* Wq      = (const float*)d_in[2];
    const float* bq      = (const float*)d_in[3];
    const float* Wv      = (const float*)d_in[4];
    const float* bv      = (const float*)d_in[5];
    const float* Wo      = (const float*)d_in[6];
    const float* bo      = (const float*)d_in[7];

    const size_t NE = (size_t)NB * SEQ * DIM;          // 8,388,608
    unsigned short* qbf = (unsigned short*)d_ws;       // 16.78 MB
    unsigned short* cbf = qbf + NE;                    // 16.78 MB
    unsigned short* hhi = cbf + NE;                    // 16.78 MB
    unsigned short* hlo = hhi + NE;                    // 16.78 MB  (total 67.1 MB)
    unsigned short* vTb = (unsigned short*)d_out;      // v^T bf16 in d_out[0:NE]
    unsigned short* qx  = ((unsigned short*)d_out) + NE; // query bf16 in d_out[NE:2NE]

    dim3 gridP(128, 4);

    conv_bf16   <<<NE / 1024, 256, 0, stream>>>(query, qx);
    conv_bf16   <<<NE / 1024, 256, 0, stream>>>(context, cbf);
    proj_sgl<0> <<<gridP, 256, 0, stream>>>(qx,  Wq, bq, qbf);
    proj_sgl<1> <<<gridP, 256, 0, stream>>>(cbf, Wv, bv, vTb);
    flash_mfma5 <<<dim3(NB, SEQ / 32), 512, 0, stream>>>(qbf, cbf, vTb, hhi, hlo);
    proj_split  <<<gridP, 256, 0, stream>>>(hhi, hlo, Wo, bo, (float*)d_out);
}

// Round 5
// 339.795 us; speedup vs baseline: 1.5018x; 1.5018x over previous
//
#include <hip/hip_runtime.h>
#include <math.h>

#define NB  8
#define SEQ 2048
#define DIM 512

typedef short v8s __attribute__((ext_vector_type(8)));
typedef float v4f __attribute__((ext_vector_type(4)));

__device__ __forceinline__ unsigned short f2bf(float f) {
    unsigned int u = __float_as_uint(f);
    u += 0x7fffu + ((u >> 16) & 1u);
    return (unsigned short)(u >> 16);
}
__device__ __forceinline__ float bf2f(unsigned short h) {
    return __uint_as_float((unsigned int)h << 16);
}
// async 16B global->LDS. LDS dest = lptr(wave-uniform) + lane*16.
__device__ __forceinline__ void async16(const unsigned short* g, unsigned short* l) {
    __builtin_amdgcn_global_load_lds(
        (const __attribute__((address_space(1))) unsigned int*)g,
        (__attribute__((address_space(3))) unsigned int*)l, 16, 0, 0);
}

// fp32 -> bf16 elementwise, two arrays in one launch (grid.y selects)
__global__ __launch_bounds__(256)
void conv_bf16_2(const float* __restrict__ x0, unsigned short* __restrict__ y0,
                 const float* __restrict__ x1, unsigned short* __restrict__ y1)
{
    const float* x = blockIdx.y ? x1 : x0;
    unsigned short* y = blockIdx.y ? y1 : y0;
    int i = blockIdx.x * 256 + threadIdx.x;
    float4 v = ((const float4*)x)[i];
    ushort4 o; o.x = f2bf(v.x); o.y = f2bf(v.y); o.z = f2bf(v.z); o.w = f2bf(v.w);
    ((ushort4*)y)[i] = o;
}

// ---------------------------------------------------------------------------
// Single-bf16 MFMA projection: Y[m][e] = sum_d X[m][d]*W[e][d] + bias[e]
// Both projections (q: row-major out, v: transposed out) in ONE launch;
// blockIdx.z selects operand set + epilogue mode.
// ---------------------------------------------------------------------------
__global__ __launch_bounds__(256, 2)
void proj_both(const unsigned short* __restrict__ X0, const float* __restrict__ W0,
               const float* __restrict__ bias0, unsigned short* __restrict__ Y0,
               const unsigned short* __restrict__ X1, const float* __restrict__ W1,
               const float* __restrict__ bias1, unsigned short* __restrict__ Y1)
{
    __shared__ __align__(16) unsigned short As[128 * 64];
    __shared__ __align__(16) unsigned short Bs[128 * 64];

    const int mode = blockIdx.z;
    const unsigned short* Xbf = mode ? X1 : X0;
    const float* W    = mode ? W1 : W0;
    const float* bias = mode ? bias1 : bias0;
    unsigned short* Y = mode ? Y1 : Y0;

    const int t = threadIdx.x, wave = t >> 6, lane = t & 63;
    const int l15 = lane & 15, quad = lane >> 4;
    const int m0 = blockIdx.x * 128, e0 = blockIdx.y * 128;

    v4f hacc[2][8];
#pragma unroll
    for (int mt = 0; mt < 2; mt++)
#pragma unroll
        for (int nt = 0; nt < 8; nt++) hacc[mt][nt] = (v4f){0.f, 0.f, 0.f, 0.f};

    const int lr8 = lane >> 3, lc8 = lane & 7;

#define STAGE_A(bk)                                                            \
    _Pragma("unroll") for (int i = 0; i < 4; i++) {                            \
        int row = wave * 32 + i * 8 + lr8;                                     \
        int lc = lc8 ^ (row & 7);                                              \
        async16(Xbf + (size_t)(m0 + row) * DIM + (bk) * 64 + lc * 8,           \
                &As[(wave * 32 + i * 8) * 64]);                                \
    }
#define STAGE_B(bk)                                                            \
    _Pragma("unroll") for (int j = 0; j < 8; j++) {                            \
        int u = t * 8 + j;                                                     \
        int row = u >> 4, c4 = u & 15;                                         \
        float4 wv = *(const float4*)(W + (size_t)(e0 + row) * DIM + (bk) * 64 + c4 * 4); \
        ushort4 o = make_ushort4(f2bf(wv.x), f2bf(wv.y), f2bf(wv.z), f2bf(wv.w)); \
        int sc = (c4 >> 1) ^ (row & 7);                                        \
        *(ushort4*)&Bs[row * 64 + sc * 8 + (c4 & 1) * 4] = o;                  \
    }

    STAGE_A(0) STAGE_B(0)
    for (int bk = 0; bk < 8; bk++) {
        __syncthreads();
#pragma unroll
        for (int kc = 0; kc < 2; kc++) {
            v8s a[2];
#pragma unroll
            for (int mt = 0; mt < 2; mt++) {
                int row = wave * 32 + mt * 16 + l15;
                a[mt] = *(const v8s*)&As[row * 64 + (((kc * 4 + quad) ^ (row & 7)) * 8)];
            }
#pragma unroll
            for (int nt = 0; nt < 8; nt++) {
                int er = nt * 16 + l15;
                v8s bfr = *(const v8s*)&Bs[er * 64 + (((kc * 4 + quad) ^ (er & 7)) * 8)];
#pragma unroll
                for (int mt = 0; mt < 2; mt++)
                    hacc[mt][nt] = __builtin_amdgcn_mfma_f32_16x16x32_bf16(a[mt], bfr, hacc[mt][nt], 0, 0, 0);
            }
        }
        __syncthreads();
        if (bk + 1 < 8) { STAGE_A(bk + 1) STAGE_B(bk + 1) }
    }
#undef STAGE_A
#undef STAGE_B

#pragma unroll
    for (int mt = 0; mt < 2; mt++)
#pragma unroll
        for (int nt = 0; nt < 8; nt++) {
            int col = e0 + nt * 16 + l15;
            float bb = bias[col];
            if (mode == 0) {
#pragma unroll
                for (int r = 0; r < 4; r++) {
                    int row = m0 + wave * 32 + mt * 16 + quad * 4 + r;
                    Y[(size_t)row * DIM + col] = f2bf(hacc[mt][nt][r] + bb);
                }
            } else {
                int rowb = m0 + wave * 32 + mt * 16 + quad * 4;
                int bidx = rowb >> 11, n = rowb & 2047;
                ushort4 o = make_ushort4(f2bf(hacc[mt][nt][0] + bb), f2bf(hacc[mt][nt][1] + bb),
                                         f2bf(hacc[mt][nt][2] + bb), f2bf(hacc[mt][nt][3] + bb));
                *(ushort4*)&Y[(size_t)bidx * DIM * SEQ + (size_t)col * SEQ + n] = o;
            }
        }
}

// ---------------------------------------------------------------------------
// Split (hi/lo) MFMA projection for the output layer: fp32-accurate.
// ---------------------------------------------------------------------------
__global__ __launch_bounds__(256, 2)
void proj_split(const unsigned short* __restrict__ Ahi, const unsigned short* __restrict__ Alo,
                const float* __restrict__ W, const float* __restrict__ bias,
                float* __restrict__ Y)
{
    __shared__ __align__(16) unsigned short Ah[128 * 64];
    __shared__ __align__(16) unsigned short Al[128 * 64];
    __shared__ __align__(16) unsigned short Bh[128 * 64];
    __shared__ __align__(16) unsigned short Bl[128 * 64];

    const int t = threadIdx.x, wave = t >> 6, lane = t & 63;
    const int l15 = lane & 15, quad = lane >> 4;
    const int m0 = blockIdx.x * 128, e0 = blockIdx.y * 128;

    v4f hacc[2][8];
#pragma unroll
    for (int mt = 0; mt < 2; mt++)
#pragma unroll
        for (int nt = 0; nt < 8; nt++) hacc[mt][nt] = (v4f){0.f, 0.f, 0.f, 0.f};

    const int lr8 = lane >> 3, lc8 = lane & 7;

#define STAGE_A2(bk)                                                           \
    _Pragma("unroll") for (int i = 0; i < 4; i++) {                            \
        int row = wave * 32 + i * 8 + lr8;                                     \
        int lc = lc8 ^ (row & 7);                                              \
        size_t ga = (size_t)(m0 + row) * DIM + (bk) * 64 + lc * 8;             \
        async16(Ahi + ga, &Ah[(wave * 32 + i * 8) * 64]);                      \
        async16(Alo + ga, &Al[(wave * 32 + i * 8) * 64]);                      \
    }
#define STAGE_B2(bk)                                                           \
    _Pragma("unroll") for (int j = 0; j < 8; j++) {                            \
        int u = t * 8 + j;                                                     \
        int row = u >> 4, c4 = u & 15;                                         \
        float4 wv = *(const float4*)(W + (size_t)(e0 + row) * DIM + (bk) * 64 + c4 * 4); \
        ushort4 oh = make_ushort4(f2bf(wv.x), f2bf(wv.y), f2bf(wv.z), f2bf(wv.w)); \
        ushort4 ol = make_ushort4(f2bf(wv.x - bf2f(oh.x)), f2bf(wv.y - bf2f(oh.y)), \
                                  f2bf(wv.z - bf2f(oh.z)), f2bf(wv.w - bf2f(oh.w))); \
        int sc = (c4 >> 1) ^ (row & 7);                                        \
        int sa = row * 64 + sc * 8 + (c4 & 1) * 4;                             \
        *(ushort4*)&Bh[sa] = oh;                                               \
        *(ushort4*)&Bl[sa] = ol;                                               \
    }

    STAGE_A2(0) STAGE_B2(0)
    for (int bk = 0; bk < 8; bk++) {
        __syncthreads();
#pragma unroll
        for (int kc = 0; kc < 2; kc++) {
            v8s ah[2], al[2];
#pragma unroll
            for (int mt = 0; mt < 2; mt++) {
                int row = wave * 32 + mt * 16 + l15;
                int sa = row * 64 + (((kc * 4 + quad) ^ (row & 7)) * 8);
                ah[mt] = *(const v8s*)&Ah[sa];
                al[mt] = *(const v8s*)&Al[sa];
            }
#pragma unroll
            for (int nt = 0; nt < 8; nt++) {
                int er = nt * 16 + l15;
                int sb = er * 64 + (((kc * 4 + quad) ^ (er & 7)) * 8);
                v8s bh = *(const v8s*)&Bh[sb];
                v8s bl = *(const v8s*)&Bl[sb];
#pragma unroll
                for (int mt = 0; mt < 2; mt++) {
                    hacc[mt][nt] = __builtin_amdgcn_mfma_f32_16x16x32_bf16(ah[mt], bh, hacc[mt][nt], 0, 0, 0);
                    hacc[mt][nt] = __builtin_amdgcn_mfma_f32_16x16x32_bf16(al[mt], bh, hacc[mt][nt], 0, 0, 0);
                    hacc[mt][nt] = __builtin_amdgcn_mfma_f32_16x16x32_bf16(ah[mt], bl, hacc[mt][nt], 0, 0, 0);
                }
            }
        }
        __syncthreads();
        if (bk + 1 < 8) { STAGE_A2(bk + 1) STAGE_B2(bk + 1) }
    }
#undef STAGE_A2
#undef STAGE_B2

#pragma unroll
    for (int mt = 0; mt < 2; mt++)
#pragma unroll
        for (int nt = 0; nt < 8; nt++) {
            int col = e0 + nt * 16 + l15;
            float bb = bias[col];
#pragma unroll
            for (int r = 0; r < 4; r++) {
                int row = m0 + wave * 32 + mt * 16 + quad * 4 + r;
                Y[(size_t)row * DIM + col] = hacc[mt][nt][r] + bb;
            }
        }
}

// ---------------------------------------------------------------------------
// Flash attention (r0-proven structure, 140 us): 512 threads (8 waves),
// 64 q-rows/block, 64-key tiles.  S: wave (strip=w&3, half=w>>2) -> 16 rows
// x 32 keys.  Softmax: fp32 S via LDS, 1 row/lane-octet.  PV: wave owns 64
// d-cols, V B-frags direct from global vT (prefetched).  K staged via
// swizzled global_load_lds during PV.  Output: h pre-split into hhi/hlo.
// ONE change vs r0: grid (NB, SEQ/64) so blockIdx.x = batch -> batch->XCD
// pinning (proven r3/r4: flash FETCH 141 MB -> ~25 MB).
// ---------------------------------------------------------------------------
__global__ __launch_bounds__(512, 2)
void flash_mfma2(const unsigned short* __restrict__ qbf,
                 const unsigned short* __restrict__ ctxbf,
                 const unsigned short* __restrict__ vT,
                 unsigned short* __restrict__ hhi,
                 unsigned short* __restrict__ hlo)
{
    __shared__ __align__(16) unsigned short Ks[64 * 512];  // swizzled [key][d]
    __shared__ __align__(16) unsigned short Ps[64 * 72];   // [row][key] bf16
    __shared__ __align__(16) float Sf[64 * 68];            // [row][key] fp32
    __shared__ float alphaS[64];

    const int t = threadIdx.x;
    const int wave = t >> 6, lane = t & 63;
    const int l15 = lane & 15, quad = lane >> 4;
    const int strip = wave & 3, half = wave >> 2;
    const int lr = lane >> 3, l8 = lane & 7;     // softmax: row wave*8+lr
    const int b = blockIdx.x, m0 = blockIdx.y * 64;

    const unsigned short* ctxb = ctxbf + (size_t)b * SEQ * DIM;
    const unsigned short* vTb  = vT    + (size_t)b * DIM * SEQ;
    const float scale = 0.044194173824159216f;   // 1/sqrt(512)

    // Q fragments: rows m0 + strip*16 + l15 (redundant across key-halves)
    v8s qf[16];
    {
        const unsigned short* qrow = qbf + ((size_t)b * SEQ + m0 + strip * 16 + l15) * DIM;
#pragma unroll
        for (int kc = 0; kc < 16; kc++)
            qf[kc] = *(const v8s*)(qrow + kc * 32 + quad * 8);
    }
    v4f hacc[4][4];   // [Mtile][dt], cols wave*64 + dt*16
#pragma unroll
    for (int m = 0; m < 4; m++)
#pragma unroll
        for (int dt = 0; dt < 4; dt++) hacc[m][dt] = (v4f){0.f, 0.f, 0.f, 0.f};

    float M = -INFINITY, L = 0.f;   // softmax state for row wave*8+lr

    // stage K[0]
#pragma unroll
    for (int i = 0; i < 8; i++) {
        int row = wave * 8 + i;
        async16(ctxb + (size_t)row * DIM + (size_t)(lane ^ (row & 7)) * 8, &Ks[row * 512]);
    }

    for (int kt = 0; kt < SEQ / 64; kt++) {
        __syncthreads();   // B0: K[kt] staged & visible
        // prefetch V fragments for this tile (consumed in PV)
        v8s vf[4][2];
#pragma unroll
        for (int dt = 0; dt < 4; dt++)
#pragma unroll
            for (int kc = 0; kc < 2; kc++)
                vf[dt][kc] = *(const v8s*)(vTb + (size_t)(wave * 64 + dt * 16 + l15) * SEQ
                                           + kt * 64 + kc * 32 + quad * 8);
        // ---- S = Q.K^T: 16 rows x 32 keys per wave ----
        v4f sacc[2];
        sacc[0] = (v4f){0.f, 0.f, 0.f, 0.f};
        sacc[1] = (v4f){0.f, 0.f, 0.f, 0.f};
#pragma unroll
        for (int kc = 0; kc < 16; kc++) {
#pragma unroll
            for (int ct = 0; ct < 2; ct++) {
                int key = half * 32 + ct * 16 + l15;
                v8s kf = *(const v8s*)&Ks[key * 512 + (((kc * 4 + quad) ^ (key & 7)) * 8)];
                sacc[ct] = __builtin_amdgcn_mfma_f32_16x16x32_bf16(qf[kc], kf, sacc[ct], 0, 0, 0);
            }
        }
#pragma unroll
        for (int ct = 0; ct < 2; ct++)
#pragma unroll
            for (int r = 0; r < 4; r++)
                Sf[(strip * 16 + quad * 4 + r) * 68 + half * 32 + ct * 16 + l15] = sacc[ct][r] * scale;
        __syncthreads();   // B1: Sf complete, Ks reads done
        // ---- softmax: row = wave*8+lr, cols l8*8.. ----
        {
            int row = wave * 8 + lr;
            float sv[8];
            *(float4*)&sv[0] = *(const float4*)&Sf[row * 68 + l8 * 8];
            *(float4*)&sv[4] = *(const float4*)&Sf[row * 68 + l8 * 8 + 4];
            float mx = sv[0];
#pragma unroll
            for (int j = 1; j < 8; j++) mx = fmaxf(mx, sv[j]);
#pragma unroll
            for (int off = 1; off < 8; off <<= 1) mx = fmaxf(mx, __shfl_xor(mx, off, 64));
            float Mn = fmaxf(M, mx);
            float al = __expf(M - Mn);
            float sm = 0.f;
            v8s pv;
#pragma unroll
            for (int j = 0; j < 8; j++) {
                float p = __expf(sv[j] - Mn);
                sm += p;
                pv[j] = (short)f2bf(p);
            }
#pragma unroll
            for (int off = 1; off < 8; off <<= 1) sm += __shfl_xor(sm, off, 64);
            L = L * al + sm;
            M = Mn;
            *(v8s*)&Ps[row * 72 + l8 * 8] = pv;
            if (l8 == 0) alphaS[row] = al;
        }
        __syncthreads();   // B2: Ps/alpha ready
        // ---- issue K[kt+1] (in flight across PV; drained at next B0) ----
        if (kt + 1 < SEQ / 64) {
#pragma unroll
            for (int i = 0; i < 8; i++) {
                int row = wave * 8 + i;
                async16(ctxb + (size_t)((kt + 1) * 64 + row) * DIM + (size_t)(lane ^ (row & 7)) * 8,
                        &Ks[row * 512]);
            }
        }
        // ---- PV: rescale + h += P.V ----
#pragma unroll
        for (int m = 0; m < 4; m++) {
            v4f a4;
#pragma unroll
            for (int r = 0; r < 4; r++) a4[r] = alphaS[m * 16 + quad * 4 + r];
#pragma unroll
            for (int dt = 0; dt < 4; dt++) hacc[m][dt] *= a4;
        }
#pragma unroll
        for (int kc = 0; kc < 2; kc++) {
            v8s pa[4];
#pragma unroll
            for (int m = 0; m < 4; m++)
                pa[m] = *(const v8s*)&Ps[(m * 16 + l15) * 72 + kc * 32 + quad * 8];
#pragma unroll
            for (int dt = 0; dt < 4; dt++)
#pragma unroll
                for (int m = 0; m < 4; m++)
                    hacc[m][dt] = __builtin_amdgcn_mfma_f32_16x16x32_bf16(pa[m], vf[dt][kc], hacc[m][dt], 0, 0, 0);
        }
    }

    // ---- epilogue: h/L, split hi/lo ----
    __syncthreads();
    if (l8 == 0) alphaS[wave * 8 + lr] = 1.0f / L;
    __syncthreads();
#pragma unroll
    for (int m = 0; m < 4; m++) {
#pragma unroll
        for (int r = 0; r < 4; r++) {
            float invL = alphaS[m * 16 + quad * 4 + r];
            int grow = m0 + m * 16 + quad * 4 + r;
#pragma unroll
            for (int dt = 0; dt < 4; dt++) {
                float o = hacc[m][dt][r] * invL;
                unsigned short hi = f2bf(o);
                float lof = o - bf2f(hi);
                size_t idx = ((size_t)b * SEQ + grow) * DIM + wave * 64 + dt * 16 + l15;
                hhi[idx] = hi;
                hlo[idx] = f2bf(lof);
            }
        }
    }
}

// ---------------------------------------------------------------------------
extern "C" void kernel_launch(void* const* d_in, const int* in_sizes, int n_in,
                              void* d_out, int out_size, void* d_ws, size_t ws_size,
                              hipStream_t stream)
{
    const float* query   = (const float*)d_in[0];
    const float* context = (const float*)d_in[1];
    const float* Wq      = (const float*)d_in[2];
    const float* bq      = (const float*)d_in[3];
    const float* Wv      = (const float*)d_in[4];
    const float* bv      = (const float*)d_in[5];
    const float* Wo      = (const float*)d_in[6];
    const float* bo      = (const float*)d_in[7];

    const size_t NE = (size_t)NB * SEQ * DIM;          // 8,388,608
    unsigned short* qbf = (unsigned short*)d_ws;       // 16.78 MB
    unsigned short* cbf = qbf + NE;                    // 16.78 MB
    unsigned short* hhi = cbf + NE;                    // 16.78 MB
    unsigned short* hlo = hhi + NE;                    // 16.78 MB  (total 67.1 MB)
    unsigned short* vTb = (unsigned short*)d_out;      // v^T bf16 in d_out[0:NE]
    unsigned short* qx  = ((unsigned short*)d_out) + NE; // query bf16 in d_out[NE:2NE]

    conv_bf16_2 <<<dim3(NE / 1024, 2), 256, 0, stream>>>(query, qx, context, cbf);
    proj_both   <<<dim3(128, 4, 2), 256, 0, stream>>>(qx,  Wq, bq, qbf,
                                                      cbf, Wv, bv, vTb);
    flash_mfma2 <<<dim3(NB, SEQ / 64), 512, 0, stream>>>(qbf, cbf, vTb, hhi, hlo);
    proj_split  <<<dim3(128, 4), 256, 0, stream>>>(hhi, hlo, Wo, bo, (float*)d_out);
}